// Round 1
// baseline (1366.412 us; speedup 1.0000x reference)
//
#include <hip/hip_runtime.h>
#include <stdint.h>
#include <stddef.h>

// ---------------- problem constants ----------------
constexpr int Dm  = 256;
constexpr int NH  = 8;
constexpr int NL  = 4;
constexpr int NP  = 4;
constexpr int DFF = 1024;
constexpr int Bb  = 2;
constexpr int Sn  = 21760;            // 128*128 + 64*64 + 32*32 + 16*16
constexpr int BS  = Bb * Sn;          // 43520  (= 340 * 128 exactly)
constexpr int DH  = Dm / NH;          // 32

// ---------------- small helpers ----------------
__device__ __forceinline__ unsigned short f2bf(float f) {
    union { float f; unsigned int u; } v; v.f = f;
    unsigned int u = v.u;
    unsigned int r = u + 0x7FFFu + ((u >> 16) & 1u);   // round-nearest-even
    return (unsigned short)(r >> 16);
}
__device__ __forceinline__ float bf2f(unsigned short h) {
    union { unsigned int u; float f; } v; v.u = ((unsigned int)h) << 16;
    return v.f;
}

typedef float  f32x4  __attribute__((ext_vector_type(4)));
typedef short  s16x8  __attribute__((ext_vector_type(8)));
typedef __bf16 bf16x8 __attribute__((ext_vector_type(8)));

// ---------------- weight convert + transpose: out[n*K+k] = bf16(in[k*N+n]) ----------------
__global__ void transpose_bf16(const float* __restrict__ in, unsigned short* __restrict__ out,
                               int K, int N) {
    int i = blockIdx.x * 256 + threadIdx.x;
    if (i >= K * N) return;
    int n = i / K, k = i - n * K;
    out[i] = f2bf(in[(size_t)k * N + n]);
}

// ---------------- q = src+pos (bf16), src (bf16) ----------------
__global__ void prep_q(const float* __restrict__ src, const float* __restrict__ pos,
                       unsigned short* __restrict__ srcb, unsigned short* __restrict__ qb,
                       int ntot) {
    for (int i = blockIdx.x * blockDim.x + threadIdx.x; i < ntot; i += gridDim.x * blockDim.x) {
        float s = src[i];
        srcb[i] = f2bf(s);
        qb[i]   = f2bf(s + pos[i]);
    }
}

// ---------------- bf16 MFMA GEMM: C(MxN) = A(MxK) * BT(NxK)^T, fused epilogues ----------------
// MODE 0: value  -> bf16 out, +bias
// MODE 1: loc    -> fp32 out = ref + (v+bias)/norm[l]
// MODE 2: attn   -> fp32 logits, +bias
// MODE 3: outproj-> fp32 out = v + bias + extra(src)
// MODE 4: ffn1   -> bf16 out = relu(v+bias)
// MODE 5: ffn2   -> fp32 out[ix] = v + bias + out[ix]   (x residual read-modify-write)
template<int MODE>
__global__ __launch_bounds__(256)
void gemm_mfma(const unsigned short* __restrict__ A,
               const unsigned short* __restrict__ BT,
               int K, int N,
               const float* __restrict__ bias,
               const float* __restrict__ extra,
               void* __restrict__ outp)
{
    __shared__ __align__(16) unsigned short As[128 * 32];
    __shared__ __align__(16) unsigned short Bs[128 * 32];

    const int tid  = threadIdx.x;
    const int lane = tid & 63;
    const int w    = tid >> 6;        // wave 0..3
    const int quad = lane >> 4;
    const int r16  = lane & 15;
    const int wr   = w >> 1, wc = w & 1;   // 2x2 wave grid, wave tile 64x64
    const int bm   = blockIdx.y, bn = blockIdx.x;

    // staging map: thread covers 16B chunks; row sr & sr+64, col sc..sc+7
    const int sr = tid >> 2;          // 0..63
    const int sc = (tid & 3) << 3;    // 0,8,16,24

    const unsigned short* gA0 = A  + (size_t)(bm * 128 + sr)      * K + sc;
    const unsigned short* gA1 = A  + (size_t)(bm * 128 + sr + 64) * K + sc;
    const unsigned short* gB0 = BT + (size_t)(bn * 128 + sr)      * K + sc;
    const unsigned short* gB1 = BT + (size_t)(bn * 128 + sr + 64) * K + sc;

    f32x4 acc[4][4] = {};

    for (int k0 = 0; k0 < K; k0 += 32) {
        s16x8 a0 = *(const s16x8*)(gA0 + k0);
        s16x8 a1 = *(const s16x8*)(gA1 + k0);
        s16x8 b0 = *(const s16x8*)(gB0 + k0);
        s16x8 b1 = *(const s16x8*)(gB1 + k0);
        __syncthreads();
        *(s16x8*)&As[sr * 32 + sc]        = a0;
        *(s16x8*)&As[(sr + 64) * 32 + sc] = a1;
        *(s16x8*)&Bs[sr * 32 + sc]        = b0;
        *(s16x8*)&Bs[(sr + 64) * 32 + sc] = b1;
        __syncthreads();

        bf16x8 af[4], bfr[4];
#pragma unroll
        for (int mt = 0; mt < 4; ++mt)
            af[mt] = *(const bf16x8*)&As[(wr * 64 + mt * 16 + r16) * 32 + quad * 8];
#pragma unroll
        for (int nt = 0; nt < 4; ++nt)
            bfr[nt] = *(const bf16x8*)&Bs[(wc * 64 + nt * 16 + r16) * 32 + quad * 8];
#pragma unroll
        for (int mt = 0; mt < 4; ++mt)
#pragma unroll
            for (int nt = 0; nt < 4; ++nt)
                acc[mt][nt] = __builtin_amdgcn_mfma_f32_16x16x32_bf16(
                    af[mt], bfr[nt], acc[mt][nt], 0, 0, 0);
    }

    // epilogue: C row = bm*128 + wr*64 + mt*16 + quad*4 + r ; col = bn*128 + wc*64 + nt*16 + r16
    const size_t ldc = (size_t)N;
    const int mbase = bm * 128 + wr * 64 + quad * 4;
    const int nbase = bn * 128 + wc * 64 + r16;
#pragma unroll
    for (int mt = 0; mt < 4; ++mt) {
#pragma unroll
        for (int nt = 0; nt < 4; ++nt) {
            const int col = nbase + nt * 16;
#pragma unroll
            for (int r = 0; r < 4; ++r) {
                const int row = mbase + mt * 16 + r;
                const float v = acc[mt][nt][r];
                if constexpr (MODE == 0) {
                    ((unsigned short*)outp)[(size_t)row * ldc + col] = f2bf(v + bias[col]);
                } else if constexpr (MODE == 1) {
                    const int c = col & 1;
                    const int l = (col >> 3) & 3;
                    const float invn = 1.f / (float)(128 >> l);   // levels square: W=H=128>>l
                    const float rp = extra[(size_t)row * 8 + l * 2 + c];
                    ((float*)outp)[(size_t)row * ldc + col] = rp + (v + bias[col]) * invn;
                } else if constexpr (MODE == 2) {
                    ((float*)outp)[(size_t)row * ldc + col] = v + bias[col];
                } else if constexpr (MODE == 3) {
                    ((float*)outp)[(size_t)row * ldc + col] =
                        v + bias[col] + extra[(size_t)row * ldc + col];
                } else if constexpr (MODE == 4) {
                    float t = v + bias[col];
                    ((unsigned short*)outp)[(size_t)row * ldc + col] = f2bf(t > 0.f ? t : 0.f);
                } else {
                    float* o = (float*)outp;
                    const size_t ix = (size_t)row * ldc + col;
                    o[ix] = v + bias[col] + o[ix];
                }
            }
        }
    }
}

// ---------------- softmax over 16 (per token*head), in place ----------------
__global__ void softmax16(float* __restrict__ a, int nrows) {
    int r = blockIdx.x * blockDim.x + threadIdx.x;
    if (r >= nrows) return;
    float* p = a + (size_t)r * 16;
    float e[16];
    float m = -1e30f;
#pragma unroll
    for (int i = 0; i < 16; ++i) { e[i] = p[i]; m = fmaxf(m, e[i]); }
    float s = 0.f;
#pragma unroll
    for (int i = 0; i < 16; ++i) { e[i] = __expf(e[i] - m); s += e[i]; }
    float inv = 1.f / s;
#pragma unroll
    for (int i = 0; i < 16; ++i) p[i] = e[i] * inv;
}

// ---------------- deformable sampling ----------------
// one block per token; thread = (h = tid>>5, d = tid&31)
__global__ __launch_bounds__(256)
void deform_sample(const unsigned short* __restrict__ val,   // (BS,256) bf16
                   const float* __restrict__ loc,            // (BS,256) fp32  (h,l,p,c)
                   const float* __restrict__ attn,           // (BS,128) fp32  (h,l,p)
                   unsigned short* __restrict__ accb)        // (BS,256) bf16
{
    __shared__ float s_attn[128];
    __shared__ float s_loc[256];
    const int t   = blockIdx.x;
    const int b   = t / Sn;
    const int tid = threadIdx.x;
    if (tid < 128) s_attn[tid] = attn[(size_t)t * 128 + tid];
    s_loc[tid] = loc[(size_t)t * 256 + tid];
    __syncthreads();

    const int h = tid >> 5, d = tid & 31;
    const int sz[4] = {128, 64, 32, 16};
    const int st[4] = {0, 16384, 20480, 21504};
    const size_t bbase = (size_t)b * Sn;

    float accv = 0.f;
#pragma unroll
    for (int l = 0; l < 4; ++l) {
        const int W = sz[l];
        const size_t lbase = bbase + st[l];
#pragma unroll
        for (int p = 0; p < 4; ++p) {
            const int idx = (h * 4 + l) * 4 + p;
            const float aw = s_attn[idx];
            const float fx = s_loc[idx * 2]     * (float)W - 0.5f;
            const float fy = s_loc[idx * 2 + 1] * (float)W - 0.5f;
            const float xf = floorf(fx), yf = floorf(fy);
            const float wx = fx - xf, wy = fy - yf;
            const int x0 = (int)xf, y0 = (int)yf;
            const int x1 = x0 + 1, y1 = y0 + 1;
            const bool xv0 = (x0 >= 0) && (x0 < W);
            const bool xv1 = (x1 >= 0) && (x1 < W);
            const bool yv0 = (y0 >= 0) && (y0 < W);
            const bool yv1 = (y1 >= 0) && (y1 < W);
            float v00 = 0.f, v01 = 0.f, v10 = 0.f, v11 = 0.f;
            if (yv0) {
                const unsigned short* rowp = val + ((lbase + (size_t)y0 * W) * 256 + h * 32 + d);
                if (xv0) v00 = bf2f(rowp[(size_t)x0 * 256]);
                if (xv1) v01 = bf2f(rowp[(size_t)x1 * 256]);
            }
            if (yv1) {
                const unsigned short* rowp = val + ((lbase + (size_t)y1 * W) * 256 + h * 32 + d);
                if (xv0) v10 = bf2f(rowp[(size_t)x0 * 256]);
                if (xv1) v11 = bf2f(rowp[(size_t)x1 * 256]);
            }
            const float sv = v00 * (1.f - wx) * (1.f - wy) + v01 * wx * (1.f - wy)
                           + v10 * (1.f - wx) * wy        + v11 * wx * wy;
            accv += aw * sv;
        }
    }
    accb[(size_t)t * 256 + tid] = f2bf(accv);
}

// ---------------- layernorm over 256, in place on io; optional bf16 emit ----------------
template<bool EMIT>
__global__ __launch_bounds__(256)
void layernorm256(float* __restrict__ io, const float* __restrict__ g,
                  const float* __restrict__ bta, unsigned short* __restrict__ xb)
{
    const int row = blockIdx.x;
    const int c   = threadIdx.x;
    float v = io[(size_t)row * 256 + c];
    float s = v, s2 = v * v;
#pragma unroll
    for (int m = 1; m < 64; m <<= 1) {
        s  += __shfl_xor(s, m);
        s2 += __shfl_xor(s2, m);
    }
    __shared__ float sh[8];
    const int wv = c >> 6, lane = c & 63;
    if (lane == 0) { sh[wv] = s; sh[4 + wv] = s2; }
    __syncthreads();
    const float ts  = sh[0] + sh[1] + sh[2] + sh[3];
    const float ts2 = sh[4] + sh[5] + sh[6] + sh[7];
    const float mu  = ts * (1.f / 256.f);
    const float var = ts2 * (1.f / 256.f) - mu * mu;
    const float inv = rsqrtf(var + 1e-5f);
    const float y = (v - mu) * inv * g[c] + bta[c];
    io[(size_t)row * 256 + c] = y;
    if constexpr (EMIT) xb[(size_t)row * 256 + c] = f2bf(y);
}

// ---------------- launch ----------------
extern "C" void kernel_launch(void* const* d_in, const int* in_sizes, int n_in,
                              void* d_out, int out_size, void* d_ws, size_t ws_size,
                              hipStream_t stream) {
    const float* src    = (const float*)d_in[0];
    const float* pos    = (const float*)d_in[1];
    const float* refpts = (const float*)d_in[2];
    // d_in[3] spatial_shapes, d_in[4] level_start_index: compile-time constants here
    const float* W_off  = (const float*)d_in[5];
    const float* b_off  = (const float*)d_in[6];
    const float* W_attn = (const float*)d_in[7];
    const float* b_attn = (const float*)d_in[8];
    const float* W_val  = (const float*)d_in[9];
    const float* b_val  = (const float*)d_in[10];
    const float* W_out  = (const float*)d_in[11];
    const float* b_out  = (const float*)d_in[12];
    const float* W_ffn1 = (const float*)d_in[13];
    const float* b_ffn1 = (const float*)d_in[14];
    const float* W_ffn2 = (const float*)d_in[15];
    const float* b_ffn2 = (const float*)d_in[16];
    const float* ln1_g  = (const float*)d_in[17];
    const float* ln1_b  = (const float*)d_in[18];
    const float* ln2_g  = (const float*)d_in[19];
    const float* ln2_b  = (const float*)d_in[20];

    char* ws = (char*)d_ws;

    // weight arena (bf16, transposed N x K)
    unsigned short* wT      = (unsigned short*)ws;
    unsigned short* WvalT   = wT + 0;        // 256x256
    unsigned short* WoffT   = wT + 65536;    // 256x256
    unsigned short* WattnT  = wT + 131072;   // 128x256
    unsigned short* WoutT   = wT + 163840;   // 256x256
    unsigned short* Wffn1T  = wT + 229376;   // 1024x256
    unsigned short* Wffn2T  = wT + 491520;   // 256x1024

    constexpr size_t SZ_TOK_BF = (size_t)BS * 256 * 2;   // 22,282,240
    constexpr size_t SZ_TOK_F  = (size_t)BS * 256 * 4;   // 44,564,480
    const size_t o = 2u * 1024 * 1024;
    unsigned short* srcb  = (unsigned short*)(ws + o);                         // later: x_bf16
    unsigned short* qb    = (unsigned short*)(ws + o + SZ_TOK_BF);             // later: acc_bf16
    unsigned short* valb  = (unsigned short*)(ws + o + 2 * SZ_TOK_BF);         // later: h_bf16 overlay
    float*          locf  = (float*)(ws + o + 3 * SZ_TOK_BF);
    float*          attnf = (float*)(ws + o + 3 * SZ_TOK_BF + SZ_TOK_F);
    unsigned short* hb    = valb;   // 89,128,960 B overlays value+loc+attn exactly
    unsigned short* xb    = srcb;
    unsigned short* accb  = qb;

    float* out = (float*)d_out;

    // 1) weights
    transpose_bf16<<<(256 * 256 + 255) / 256, 256, 0, stream>>>(W_val,  WvalT,  256, 256);
    transpose_bf16<<<(256 * 256 + 255) / 256, 256, 0, stream>>>(W_off,  WoffT,  256, 256);
    transpose_bf16<<<(256 * 128 + 255) / 256, 256, 0, stream>>>(W_attn, WattnT, 256, 128);
    transpose_bf16<<<(256 * 256 + 255) / 256, 256, 0, stream>>>(W_out,  WoutT,  256, 256);
    transpose_bf16<<<(256 * 1024 + 255) / 256, 256, 0, stream>>>(W_ffn1, Wffn1T, 256, 1024);
    transpose_bf16<<<(256 * 1024 + 255) / 256, 256, 0, stream>>>(W_ffn2, Wffn2T, 1024, 256);

    // 2) activations prep
    prep_q<<<4096, 256, 0, stream>>>(src, pos, srcb, qb, BS * 256);

    dim3 g1(1, BS / 128), g2(2, BS / 128), g8(8, BS / 128);
    // 3) value projection -> bf16
    gemm_mfma<0><<<g2, 256, 0, stream>>>(srcb, WvalT, 256, 256, b_val, nullptr, valb);
    // 4) offsets -> sampling locations (fused)
    gemm_mfma<1><<<g2, 256, 0, stream>>>(qb, WoffT, 256, 256, b_off, refpts, locf);
    // 5) attention logits
    gemm_mfma<2><<<g1, 256, 0, stream>>>(qb, WattnT, 256, 128, b_attn, nullptr, attnf);
    // 6) softmax over (l,p)
    softmax16<<<(BS * NH + 255) / 256, 256, 0, stream>>>(attnf, BS * NH);
    // 7) deformable bilinear sampling + weighted sum
    deform_sample<<<BS, 256, 0, stream>>>(valb, locf, attnf, accb);
    // 8) output projection + residual (src) -> d_out (fp32)
    gemm_mfma<3><<<g2, 256, 0, stream>>>(accb, WoutT, 256, 256, b_out, src, out);
    // 9) LN1 in place, emit x bf16
    layernorm256<true><<<BS, 256, 0, stream>>>(out, ln1_g, ln1_b, xb);
    // 10) FFN1 + relu -> bf16
    gemm_mfma<4><<<g8, 256, 0, stream>>>(xb, Wffn1T, 256, 1024, b_ffn1, nullptr, hb);
    // 11) FFN2 + residual(x, read from d_out) -> d_out
    gemm_mfma<5><<<g2, 256, 0, stream>>>(hb, Wffn2T, 1024, 256, b_ffn2, nullptr, out);
    // 12) LN2 in place
    layernorm256<false><<<BS, 256, 0, stream>>>(out, ln2_g, ln2_b, nullptr);
}

// Round 2
// 550.265 us; speedup vs baseline: 2.4832x; 2.4832x over previous
//
#include <hip/hip_runtime.h>
#include <stdint.h>
#include <stddef.h>

// ---------------- problem constants ----------------
constexpr int Dm  = 256;
constexpr int NH  = 8;
constexpr int NL  = 4;
constexpr int NP  = 4;
constexpr int DFF = 1024;
constexpr int Bb  = 2;
constexpr int Sn  = 21760;            // 128*128 + 64*64 + 32*32 + 16*16
constexpr int BS  = Bb * Sn;          // 43520  (= 340 * 128 exactly)
constexpr int DH  = Dm / NH;          // 32

// ---------------- small helpers ----------------
__device__ __forceinline__ unsigned short f2bf(float f) {
    union { float f; unsigned int u; } v; v.f = f;
    unsigned int u = v.u;
    unsigned int r = u + 0x7FFFu + ((u >> 16) & 1u);   // round-nearest-even
    return (unsigned short)(r >> 16);
}
__device__ __forceinline__ float bf2f(unsigned short h) {
    union { unsigned int u; float f; } v; v.u = ((unsigned int)h) << 16;
    return v.f;
}
__device__ __forceinline__ float u2f_lo(unsigned int u) {
    union { unsigned int u; float f; } v; v.u = u << 16; return v.f;
}
__device__ __forceinline__ float u2f_hi(unsigned int u) {
    union { unsigned int u; float f; } v; v.u = u & 0xFFFF0000u; return v.f;
}

typedef float  f32x4  __attribute__((ext_vector_type(4)));
typedef short  s16x8  __attribute__((ext_vector_type(8)));
typedef __bf16 bf16x8 __attribute__((ext_vector_type(8)));

// ---------------- weight convert + transpose: out[n*K+k] = bf16(in[k*N+n]) ----------------
__global__ void transpose_bf16(const float* __restrict__ in, unsigned short* __restrict__ out,
                               int K, int N) {
    int i = blockIdx.x * 256 + threadIdx.x;
    if (i >= K * N) return;
    int n = i / K, k = i - n * K;
    out[i] = f2bf(in[(size_t)k * N + n]);
}

// ---------------- q = src+pos (bf16), src (bf16) ----------------
__global__ void prep_q(const float* __restrict__ src, const float* __restrict__ pos,
                       unsigned short* __restrict__ srcb, unsigned short* __restrict__ qb,
                       int ntot) {
    for (int i = blockIdx.x * blockDim.x + threadIdx.x; i < ntot; i += gridDim.x * blockDim.x) {
        float s = src[i];
        srcb[i] = f2bf(s);
        qb[i]   = f2bf(s + pos[i]);
    }
}

// ---------------- bf16 MFMA GEMM: C(MxN) = A(MxK) * BT(NxK)^T, fused epilogues ----------------
// MODE 0: value  -> bf16 out, +bias
// MODE 1: loc    -> fp32 out = ref + (v+bias)/norm[l]
// MODE 2: attn   -> fp32 logits, +bias
// MODE 3: outproj-> fp32 out = v + bias + extra(src)
// MODE 4: ffn1   -> bf16 out = relu(v+bias)
// MODE 5: ffn2   -> fp32 out[ix] = v + bias + out[ix]   (x residual read-modify-write)
template<int MODE>
__global__ __launch_bounds__(256)
void gemm_mfma(const unsigned short* __restrict__ A,
               const unsigned short* __restrict__ BT,
               int K, int N,
               const float* __restrict__ bias,
               const float* __restrict__ extra,
               void* __restrict__ outp)
{
    __shared__ __align__(16) unsigned short As[128 * 32];
    __shared__ __align__(16) unsigned short Bs[128 * 32];

    const int tid  = threadIdx.x;
    const int lane = tid & 63;
    const int w    = tid >> 6;        // wave 0..3
    const int quad = lane >> 4;
    const int r16  = lane & 15;
    const int wr   = w >> 1, wc = w & 1;   // 2x2 wave grid, wave tile 64x64
    const int bm   = blockIdx.y, bn = blockIdx.x;

    // staging map: thread covers 16B chunks; row sr & sr+64, col sc..sc+7
    const int sr = tid >> 2;          // 0..63
    const int sc = (tid & 3) << 3;    // 0,8,16,24

    const unsigned short* gA0 = A  + (size_t)(bm * 128 + sr)      * K + sc;
    const unsigned short* gA1 = A  + (size_t)(bm * 128 + sr + 64) * K + sc;
    const unsigned short* gB0 = BT + (size_t)(bn * 128 + sr)      * K + sc;
    const unsigned short* gB1 = BT + (size_t)(bn * 128 + sr + 64) * K + sc;

    f32x4 acc[4][4] = {};

    for (int k0 = 0; k0 < K; k0 += 32) {
        s16x8 a0 = *(const s16x8*)(gA0 + k0);
        s16x8 a1 = *(const s16x8*)(gA1 + k0);
        s16x8 b0 = *(const s16x8*)(gB0 + k0);
        s16x8 b1 = *(const s16x8*)(gB1 + k0);
        __syncthreads();
        *(s16x8*)&As[sr * 32 + sc]        = a0;
        *(s16x8*)&As[(sr + 64) * 32 + sc] = a1;
        *(s16x8*)&Bs[sr * 32 + sc]        = b0;
        *(s16x8*)&Bs[(sr + 64) * 32 + sc] = b1;
        __syncthreads();

        bf16x8 af[4], bfr[4];
#pragma unroll
        for (int mt = 0; mt < 4; ++mt)
            af[mt] = *(const bf16x8*)&As[(wr * 64 + mt * 16 + r16) * 32 + quad * 8];
#pragma unroll
        for (int nt = 0; nt < 4; ++nt)
            bfr[nt] = *(const bf16x8*)&Bs[(wc * 64 + nt * 16 + r16) * 32 + quad * 8];
#pragma unroll
        for (int mt = 0; mt < 4; ++mt)
#pragma unroll
            for (int nt = 0; nt < 4; ++nt)
                acc[mt][nt] = __builtin_amdgcn_mfma_f32_16x16x32_bf16(
                    af[mt], bfr[nt], acc[mt][nt], 0, 0, 0);
    }

    // epilogue: C row = bm*128 + wr*64 + mt*16 + quad*4 + r ; col = bn*128 + wc*64 + nt*16 + r16
    const size_t ldc = (size_t)N;
    const int mbase = bm * 128 + wr * 64 + quad * 4;
    const int nbase = bn * 128 + wc * 64 + r16;
#pragma unroll
    for (int mt = 0; mt < 4; ++mt) {
#pragma unroll
        for (int nt = 0; nt < 4; ++nt) {
            const int col = nbase + nt * 16;
#pragma unroll
            for (int r = 0; r < 4; ++r) {
                const int row = mbase + mt * 16 + r;
                const float v = acc[mt][nt][r];
                if constexpr (MODE == 0) {
                    ((unsigned short*)outp)[(size_t)row * ldc + col] = f2bf(v + bias[col]);
                } else if constexpr (MODE == 1) {
                    const int c = col & 1;
                    const int l = (col >> 3) & 3;
                    const float invn = 1.f / (float)(128 >> l);   // levels square: W=H=128>>l
                    const float rp = extra[(size_t)row * 8 + l * 2 + c];
                    ((float*)outp)[(size_t)row * ldc + col] = rp + (v + bias[col]) * invn;
                } else if constexpr (MODE == 2) {
                    ((float*)outp)[(size_t)row * ldc + col] = v + bias[col];
                } else if constexpr (MODE == 3) {
                    ((float*)outp)[(size_t)row * ldc + col] =
                        v + bias[col] + extra[(size_t)row * ldc + col];
                } else if constexpr (MODE == 4) {
                    float t = v + bias[col];
                    ((unsigned short*)outp)[(size_t)row * ldc + col] = f2bf(t > 0.f ? t : 0.f);
                } else {
                    float* o = (float*)outp;
                    const size_t ix = (size_t)row * ldc + col;
                    o[ix] = v + bias[col] + o[ix];
                }
            }
        }
    }
}

// ---------------- softmax over 16 (per token*head), in place ----------------
__global__ void softmax16(float* __restrict__ a, int nrows) {
    int r = blockIdx.x * blockDim.x + threadIdx.x;
    if (r >= nrows) return;
    float* p = a + (size_t)r * 16;
    float e[16];
    float m = -1e30f;
#pragma unroll
    for (int i = 0; i < 16; ++i) { e[i] = p[i]; m = fmaxf(m, e[i]); }
    float s = 0.f;
#pragma unroll
    for (int i = 0; i < 16; ++i) { e[i] = __expf(e[i] - m); s += e[i]; }
    float inv = 1.f / s;
#pragma unroll
    for (int i = 0; i < 16; ++i) p[i] = e[i] * inv;
}

// ---------------- deformable sampling, v2 ----------------
// 8 tokens per block of 256. thread = (tk = tid>>5, h = (tid>>2)&7, c4 = tid&3).
// Each thread owns 8 channels (16B) and accumulates over all 16 points x 4 corners:
// unconditional clamped 16B gathers, validity folded into the bilinear weights.
__global__ __launch_bounds__(256)
void deform_sample(const unsigned short* __restrict__ val,   // (BS,256) bf16
                   const float* __restrict__ loc,            // (BS,256) fp32  (h,l,p,c)
                   const float* __restrict__ attn,           // (BS,128) fp32  (h,l,p)
                   unsigned short* __restrict__ accb)        // (BS,256) bf16
{
    // head-minor LDS layouts: bank = f(c2,h); 8 distinct h -> 8 banks, tk pair -> 2-way (free)
    __shared__ float s_loc[8][32][8];    // [tk][pl*2+c][h]
    __shared__ float s_attn[8][16][8];   // [tk][pl][h]

    const int tid = threadIdx.x;
    const int t0  = blockIdx.x * 8;

    for (int i = tid; i < 8 * 256; i += 256) {
        const int tk = i >> 8, rem = i & 255;
        const int hh = rem >> 5, off = rem & 31;   // off = pl*2+c
        s_loc[tk][off][hh] = loc[(size_t)t0 * 256 + i];
    }
    for (int i = tid; i < 8 * 128; i += 256) {
        const int tk = i >> 7, rem = i & 127;
        const int hh = rem >> 4, pl = rem & 15;
        s_attn[tk][pl][hh] = attn[(size_t)t0 * 128 + i];
    }
    __syncthreads();

    const int c4 = tid & 3;
    const int h  = (tid >> 2) & 7;
    const int tk = tid >> 5;
    const int t  = t0 + tk;
    const int b  = t0 / Sn;                         // Sn % 8 == 0 -> whole block same batch

    const int sz[4] = {128, 64, 32, 16};
    const int st[4] = {0, 16384, 20480, 21504};

    // per-thread channel base: batch + head + channel-group (16B aligned)
    const unsigned short* valh = val + ((size_t)b * Sn) * 256 + h * 32 + c4 * 8;

    const float* slh = &s_loc[tk][0][h];    // stride 8 floats per c2
    const float* sah = &s_attn[tk][0][h];   // stride 8 floats per pl

    float acc[8] = {0.f, 0.f, 0.f, 0.f, 0.f, 0.f, 0.f, 0.f};

#pragma unroll
    for (int l = 0; l < 4; ++l) {
        const int W = sz[l];
        const float Wf = (float)W;
        const unsigned short* lptr = valh + (size_t)st[l] * 256;
#pragma unroll
        for (int p = 0; p < 4; ++p) {
            const int pl = l * 4 + p;
            const float aw = sah[pl * 8];
            const float fx = slh[(pl * 2) * 8]     * Wf - 0.5f;
            const float fy = slh[(pl * 2 + 1) * 8] * Wf - 0.5f;
            const float xf = floorf(fx), yf = floorf(fy);
            const float wx = fx - xf,  wy = fy - yf;
            const int x0 = (int)xf, y0 = (int)yf;
            const int x1 = x0 + 1,  y1 = y0 + 1;
            // validity as 0/1 weights; clamped addresses keep loads in-bounds
            const float vx0 = (x0 >= 0 && x0 < W) ? 1.f : 0.f;
            const float vx1 = (x1 >= 0 && x1 < W) ? 1.f : 0.f;
            const float vy0 = (y0 >= 0 && y0 < W) ? 1.f : 0.f;
            const float vy1 = (y1 >= 0 && y1 < W) ? 1.f : 0.f;
            const int x0c = min(max(x0, 0), W - 1);
            const int x1c = min(max(x1, 0), W - 1);
            const int y0c = min(max(y0, 0), W - 1);
            const int y1c = min(max(y1, 0), W - 1);

            const float w00 = aw * (1.f - wx) * (1.f - wy) * vx0 * vy0;
            const float w01 = aw * wx         * (1.f - wy) * vx1 * vy0;
            const float w10 = aw * (1.f - wx) * wy         * vx0 * vy1;
            const float w11 = aw * wx         * wy         * vx1 * vy1;

            const uint4 u00 = *(const uint4*)(lptr + (size_t)((y0c * W + x0c) << 8));
            const uint4 u01 = *(const uint4*)(lptr + (size_t)((y0c * W + x1c) << 8));
            const uint4 u10 = *(const uint4*)(lptr + (size_t)((y1c * W + x0c) << 8));
            const uint4 u11 = *(const uint4*)(lptr + (size_t)((y1c * W + x1c) << 8));

            acc[0] += w00 * u2f_lo(u00.x); acc[1] += w00 * u2f_hi(u00.x);
            acc[2] += w00 * u2f_lo(u00.y); acc[3] += w00 * u2f_hi(u00.y);
            acc[4] += w00 * u2f_lo(u00.z); acc[5] += w00 * u2f_hi(u00.z);
            acc[6] += w00 * u2f_lo(u00.w); acc[7] += w00 * u2f_hi(u00.w);

            acc[0] += w01 * u2f_lo(u01.x); acc[1] += w01 * u2f_hi(u01.x);
            acc[2] += w01 * u2f_lo(u01.y); acc[3] += w01 * u2f_hi(u01.y);
            acc[4] += w01 * u2f_lo(u01.z); acc[5] += w01 * u2f_hi(u01.z);
            acc[6] += w01 * u2f_lo(u01.w); acc[7] += w01 * u2f_hi(u01.w);

            acc[0] += w10 * u2f_lo(u10.x); acc[1] += w10 * u2f_hi(u10.x);
            acc[2] += w10 * u2f_lo(u10.y); acc[3] += w10 * u2f_hi(u10.y);
            acc[4] += w10 * u2f_lo(u10.z); acc[5] += w10 * u2f_hi(u10.z);
            acc[6] += w10 * u2f_lo(u10.w); acc[7] += w10 * u2f_hi(u10.w);

            acc[0] += w11 * u2f_lo(u11.x); acc[1] += w11 * u2f_hi(u11.x);
            acc[2] += w11 * u2f_lo(u11.y); acc[3] += w11 * u2f_hi(u11.y);
            acc[4] += w11 * u2f_lo(u11.z); acc[5] += w11 * u2f_hi(u11.z);
            acc[6] += w11 * u2f_lo(u11.w); acc[7] += w11 * u2f_hi(u11.w);
        }
    }

    // pack 8 bf16 -> 16B coalesced store
    uint4 o;
    o.x = (unsigned int)f2bf(acc[0]) | ((unsigned int)f2bf(acc[1]) << 16);
    o.y = (unsigned int)f2bf(acc[2]) | ((unsigned int)f2bf(acc[3]) << 16);
    o.z = (unsigned int)f2bf(acc[4]) | ((unsigned int)f2bf(acc[5]) << 16);
    o.w = (unsigned int)f2bf(acc[6]) | ((unsigned int)f2bf(acc[7]) << 16);
    *(uint4*)(accb + (size_t)t * 256 + h * 32 + c4 * 8) = o;
}

// ---------------- layernorm over 256, in place on io; optional bf16 emit ----------------
template<bool EMIT>
__global__ __launch_bounds__(256)
void layernorm256(float* __restrict__ io, const float* __restrict__ g,
                  const float* __restrict__ bta, unsigned short* __restrict__ xb)
{
    const int row = blockIdx.x;
    const int c   = threadIdx.x;
    float v = io[(size_t)row * 256 + c];
    float s = v, s2 = v * v;
#pragma unroll
    for (int m = 1; m < 64; m <<= 1) {
        s  += __shfl_xor(s, m);
        s2 += __shfl_xor(s2, m);
    }
    __shared__ float sh[8];
    const int wv = c >> 6, lane = c & 63;
    if (lane == 0) { sh[wv] = s; sh[4 + wv] = s2; }
    __syncthreads();
    const float ts  = sh[0] + sh[1] + sh[2] + sh[3];
    const float ts2 = sh[4] + sh[5] + sh[6] + sh[7];
    const float mu  = ts * (1.f / 256.f);
    const float var = ts2 * (1.f / 256.f) - mu * mu;
    const float inv = rsqrtf(var + 1e-5f);
    const float y = (v - mu) * inv * g[c] + bta[c];
    io[(size_t)row * 256 + c] = y;
    if constexpr (EMIT) xb[(size_t)row * 256 + c] = f2bf(y);
}

// ---------------- launch ----------------
extern "C" void kernel_launch(void* const* d_in, const int* in_sizes, int n_in,
                              void* d_out, int out_size, void* d_ws, size_t ws_size,
                              hipStream_t stream) {
    const float* src    = (const float*)d_in[0];
    const float* pos    = (const float*)d_in[1];
    const float* refpts = (const float*)d_in[2];
    const float* W_off  = (const float*)d_in[5];
    const float* b_off  = (const float*)d_in[6];
    const float* W_attn = (const float*)d_in[7];
    const float* b_attn = (const float*)d_in[8];
    const float* W_val  = (const float*)d_in[9];
    const float* b_val  = (const float*)d_in[10];
    const float* W_out  = (const float*)d_in[11];
    const float* b_out  = (const float*)d_in[12];
    const float* W_ffn1 = (const float*)d_in[13];
    const float* b_ffn1 = (const float*)d_in[14];
    const float* W_ffn2 = (const float*)d_in[15];
    const float* b_ffn2 = (const float*)d_in[16];
    const float* ln1_g  = (const float*)d_in[17];
    const float* ln1_b  = (const float*)d_in[18];
    const float* ln2_g  = (const float*)d_in[19];
    const float* ln2_b  = (const float*)d_in[20];

    char* ws = (char*)d_ws;

    // weight arena (bf16, transposed N x K)
    unsigned short* wT      = (unsigned short*)ws;
    unsigned short* WvalT   = wT + 0;        // 256x256
    unsigned short* WoffT   = wT + 65536;    // 256x256
    unsigned short* WattnT  = wT + 131072;   // 128x256
    unsigned short* WoutT   = wT + 163840;   // 256x256
    unsigned short* Wffn1T  = wT + 229376;   // 1024x256
    unsigned short* Wffn2T  = wT + 491520;   // 256x1024

    constexpr size_t SZ_TOK_BF = (size_t)BS * 256 * 2;   // 22,282,240
    constexpr size_t SZ_TOK_F  = (size_t)BS * 256 * 4;   // 44,564,480
    const size_t o = 2u * 1024 * 1024;
    unsigned short* srcb  = (unsigned short*)(ws + o);                         // later: x_bf16
    unsigned short* qb    = (unsigned short*)(ws + o + SZ_TOK_BF);             // later: acc_bf16
    unsigned short* valb  = (unsigned short*)(ws + o + 2 * SZ_TOK_BF);         // later: h_bf16 overlay
    float*          locf  = (float*)(ws + o + 3 * SZ_TOK_BF);
    float*          attnf = (float*)(ws + o + 3 * SZ_TOK_BF + SZ_TOK_F);
    unsigned short* hb    = valb;   // 89,128,960 B overlays value+loc+attn exactly
    unsigned short* xb    = srcb;
    unsigned short* accb  = qb;

    float* out = (float*)d_out;

    // 1) weights
    transpose_bf16<<<(256 * 256 + 255) / 256, 256, 0, stream>>>(W_val,  WvalT,  256, 256);
    transpose_bf16<<<(256 * 256 + 255) / 256, 256, 0, stream>>>(W_off,  WoffT,  256, 256);
    transpose_bf16<<<(256 * 128 + 255) / 256, 256, 0, stream>>>(W_attn, WattnT, 256, 128);
    transpose_bf16<<<(256 * 256 + 255) / 256, 256, 0, stream>>>(W_out,  WoutT,  256, 256);
    transpose_bf16<<<(256 * 1024 + 255) / 256, 256, 0, stream>>>(W_ffn1, Wffn1T, 256, 1024);
    transpose_bf16<<<(256 * 1024 + 255) / 256, 256, 0, stream>>>(W_ffn2, Wffn2T, 1024, 256);

    // 2) activations prep
    prep_q<<<4096, 256, 0, stream>>>(src, pos, srcb, qb, BS * 256);

    dim3 g1(1, BS / 128), g2(2, BS / 128), g8(8, BS / 128);
    // 3) value projection -> bf16
    gemm_mfma<0><<<g2, 256, 0, stream>>>(srcb, WvalT, 256, 256, b_val, nullptr, valb);
    // 4) offsets -> sampling locations (fused)
    gemm_mfma<1><<<g2, 256, 0, stream>>>(qb, WoffT, 256, 256, b_off, refpts, locf);
    // 5) attention logits
    gemm_mfma<2><<<g1, 256, 0, stream>>>(qb, WattnT, 256, 128, b_attn, nullptr, attnf);
    // 6) softmax over (l,p)
    softmax16<<<(BS * NH + 255) / 256, 256, 0, stream>>>(attnf, BS * NH);
    // 7) deformable bilinear sampling + weighted sum (v2: 16B gathers, 8 tokens/block)
    deform_sample<<<BS / 8, 256, 0, stream>>>(valb, locf, attnf, accb);
    // 8) output projection + residual (src) -> d_out (fp32)
    gemm_mfma<3><<<g2, 256, 0, stream>>>(accb, WoutT, 256, 256, b_out, src, out);
    // 9) LN1 in place, emit x bf16
    layernorm256<true><<<BS, 256, 0, stream>>>(out, ln1_g, ln1_b, xb);
    // 10) FFN1 + relu -> bf16
    gemm_mfma<4><<<g8, 256, 0, stream>>>(xb, Wffn1T, 256, 1024, b_ffn1, nullptr, hb);
    // 11) FFN2 + residual(x, read from d_out) -> d_out
    gemm_mfma<5><<<g2, 256, 0, stream>>>(hb, Wffn2T, 1024, 256, b_ffn2, nullptr, out);
    // 12) LN2 in place
    layernorm256<false><<<BS, 256, 0, stream>>>(out, ln2_g, ln2_b, nullptr);
}

// Round 3
// 528.776 us; speedup vs baseline: 2.5841x; 1.0406x over previous
//
#include <hip/hip_runtime.h>
#include <stdint.h>
#include <stddef.h>

// ---------------- problem constants ----------------
constexpr int Dm  = 256;
constexpr int NH  = 8;
constexpr int NL  = 4;
constexpr int NP  = 4;
constexpr int DFF = 1024;
constexpr int Bb  = 2;
constexpr int Sn  = 21760;            // 128*128 + 64*64 + 32*32 + 16*16
constexpr int BS  = Bb * Sn;          // 43520  (= 340 * 128 exactly)
constexpr int DH  = Dm / NH;          // 32

// ---------------- small helpers ----------------
__device__ __forceinline__ unsigned short f2bf(float f) {
    union { float f; unsigned int u; } v; v.f = f;
    unsigned int u = v.u;
    unsigned int r = u + 0x7FFFu + ((u >> 16) & 1u);   // round-nearest-even
    return (unsigned short)(r >> 16);
}
__device__ __forceinline__ float bf2f(unsigned short h) {
    union { unsigned int u; float f; } v; v.u = ((unsigned int)h) << 16;
    return v.f;
}

typedef float  f32x4  __attribute__((ext_vector_type(4)));
typedef float  f32x2  __attribute__((ext_vector_type(2)));
typedef short  s16x8  __attribute__((ext_vector_type(8)));
typedef __bf16 bf16x8 __attribute__((ext_vector_type(8)));

// unpack 2 bf16 (packed in u32) -> float2
__device__ __forceinline__ f32x2 cvt2(unsigned int u) {
    union { unsigned int u; float f; } lo, hi;
    lo.u = u << 16; hi.u = u & 0xFFFF0000u;
    f32x2 r; r.x = lo.f; r.y = hi.f; return r;
}

// address-space helpers for global_load_lds
typedef const __attribute__((address_space(1))) unsigned int GU;
typedef __attribute__((address_space(3))) unsigned int LU;
__device__ __forceinline__ void g2lds16(const void* g, void* l) {
    __builtin_amdgcn_global_load_lds((GU*)g, (LU*)l, 16, 0, 0);
}

// ---------------- all weights: convert + transpose in ONE kernel ----------------
// wT element layout: val@0(64K) off@64K attn@128K(32K) out@160K ffn1@224K(256K) ffn2@480K(256K)
__global__ void transpose_all(const float* __restrict__ W_val, const float* __restrict__ W_off,
                              const float* __restrict__ W_attn, const float* __restrict__ W_out,
                              const float* __restrict__ W_ffn1, const float* __restrict__ W_ffn2,
                              unsigned short* __restrict__ wT) {
    int i = blockIdx.x * 256 + threadIdx.x;
    const float* src; int K, N, base;
    if      (i < 65536)  { src = W_val;  K = 256;  N = 256;  base = 0; }
    else if (i < 131072) { src = W_off;  K = 256;  N = 256;  base = 65536; }
    else if (i < 163840) { src = W_attn; K = 256;  N = 128;  base = 131072; }
    else if (i < 229376) { src = W_out;  K = 256;  N = 256;  base = 163840; }
    else if (i < 491520) { src = W_ffn1; K = 256;  N = 1024; base = 229376; }
    else if (i < 753664) { src = W_ffn2; K = 1024; N = 256;  base = 491520; }
    else return;
    int j = i - base;
    int n = j / K, k = j - n * K;
    wT[i] = f2bf(src[(size_t)k * N + n]);
}

// ---------------- q = src+pos (bf16), src (bf16) ----------------
__global__ void prep_q(const float* __restrict__ src, const float* __restrict__ pos,
                       unsigned short* __restrict__ srcb, unsigned short* __restrict__ qb,
                       int ntot) {
    for (int i = blockIdx.x * blockDim.x + threadIdx.x; i < ntot; i += gridDim.x * blockDim.x) {
        float s = src[i];
        srcb[i] = f2bf(s);
        qb[i]   = f2bf(s + pos[i]);
    }
}

// ---------------- bf16 MFMA GEMM: C(MxN) = A(MxK) * BT(NxK)^T, fused epilogues ----------------
// Staging is async global->LDS (global_load_lds width=16), m97 2-barrier K-loop.
// MODE 0: value  -> bf16 out, +bias
// MODE 1: loc    -> fp32 out = ref + (v+bias)/norm[l]
// MODE 2: attn   -> fp32 out = softmax16(v+bias)   (softmax fused via quad shfl)
// MODE 3: outproj-> fp32 out = v + bias + extra(src)
// MODE 4: ffn1   -> bf16 out = relu(v+bias)
// MODE 5: ffn2   -> fp32 out[ix] = v + bias + out[ix]   (x residual read-modify-write)
template<int MODE>
__global__ __launch_bounds__(256)
void gemm_mfma(const unsigned short* __restrict__ A,
               const unsigned short* __restrict__ BT,
               int K, int N,
               const float* __restrict__ bias,
               const float* __restrict__ extra,
               void* __restrict__ outp)
{
    __shared__ __align__(16) unsigned short As[128 * 32];
    __shared__ __align__(16) unsigned short Bs[128 * 32];

    const int tid  = threadIdx.x;
    const int lane = tid & 63;
    const int w    = tid >> 6;        // wave 0..3
    const int quad = lane >> 4;
    const int r16  = lane & 15;
    const int wr   = w >> 1, wc = w & 1;   // 2x2 wave grid, wave tile 64x64
    const int bm   = blockIdx.y, bn = blockIdx.x;

    // staging map: LDS byte offset == tid*16 (lane-contiguous per wave -> global_load_lds legal)
    const int sr = tid >> 2;          // 0..63
    const int sc = (tid & 3) << 3;    // 0,8,16,24

    const unsigned short* gA0 = A  + (size_t)(bm * 128 + sr)      * K + sc;
    const unsigned short* gA1 = A  + (size_t)(bm * 128 + sr + 64) * K + sc;
    const unsigned short* gB0 = BT + (size_t)(bn * 128 + sr)      * K + sc;
    const unsigned short* gB1 = BT + (size_t)(bn * 128 + sr + 64) * K + sc;

    char* AsB = (char*)As;
    char* BsB = (char*)Bs;
    const int woff = w * 1024;        // wave-uniform LDS region base

    f32x4 acc[4][4] = {};

    for (int k0 = 0; k0 < K; k0 += 32) {
        __syncthreads();              // previous compute done before LDS overwrite
        g2lds16(gA0 + k0, AsB + woff);
        g2lds16(gA1 + k0, AsB + 4096 + woff);
        g2lds16(gB0 + k0, BsB + woff);
        g2lds16(gB1 + k0, BsB + 4096 + woff);
        __syncthreads();              // drains vmcnt (compiler emits s_waitcnt before barrier)

        bf16x8 af[4], bfr[4];
#pragma unroll
        for (int mt = 0; mt < 4; ++mt)
            af[mt] = *(const bf16x8*)&As[(wr * 64 + mt * 16 + r16) * 32 + quad * 8];
#pragma unroll
        for (int nt = 0; nt < 4; ++nt)
            bfr[nt] = *(const bf16x8*)&Bs[(wc * 64 + nt * 16 + r16) * 32 + quad * 8];
#pragma unroll
        for (int mt = 0; mt < 4; ++mt)
#pragma unroll
            for (int nt = 0; nt < 4; ++nt)
                acc[mt][nt] = __builtin_amdgcn_mfma_f32_16x16x32_bf16(
                    af[mt], bfr[nt], acc[mt][nt], 0, 0, 0);
    }

    // epilogue: C row = bm*128 + wr*64 + mt*16 + quad*4 + r ; col = bn*128 + wc*64 + nt*16 + r16
    const size_t ldc = (size_t)N;
    const int mbase = bm * 128 + wr * 64 + quad * 4;
    const int nbase = bn * 128 + wc * 64 + r16;
#pragma unroll
    for (int mt = 0; mt < 4; ++mt) {
#pragma unroll
        for (int nt = 0; nt < 4; ++nt) {
            const int col = nbase + nt * 16;
#pragma unroll
            for (int r = 0; r < 4; ++r) {
                const int row = mbase + mt * 16 + r;
                const float v = acc[mt][nt][r];
                if constexpr (MODE == 0) {
                    ((unsigned short*)outp)[(size_t)row * ldc + col] = f2bf(v + bias[col]);
                } else if constexpr (MODE == 1) {
                    const int c = col & 1;
                    const int l = (col >> 3) & 3;
                    const float invn = 1.f / (float)(128 >> l);   // levels square: W=H=128>>l
                    const float rp = extra[(size_t)row * 8 + l * 2 + c];
                    ((float*)outp)[(size_t)row * ldc + col] = rp + (v + bias[col]) * invn;
                } else if constexpr (MODE == 2) {
                    // fused softmax over 16 cols of one (token,head): the 16 r16-lanes of
                    // this quad hold exactly that group (xor masks 1,2,4,8 stay in-quad).
                    float x = v + bias[col];
                    float mx = x;
                    mx = fmaxf(mx, __shfl_xor(mx, 1));
                    mx = fmaxf(mx, __shfl_xor(mx, 2));
                    mx = fmaxf(mx, __shfl_xor(mx, 4));
                    mx = fmaxf(mx, __shfl_xor(mx, 8));
                    float e = __expf(x - mx);
                    float s = e;
                    s += __shfl_xor(s, 1);
                    s += __shfl_xor(s, 2);
                    s += __shfl_xor(s, 4);
                    s += __shfl_xor(s, 8);
                    ((float*)outp)[(size_t)row * ldc + col] = e / s;
                } else if constexpr (MODE == 3) {
                    ((float*)outp)[(size_t)row * ldc + col] =
                        v + bias[col] + extra[(size_t)row * ldc + col];
                } else if constexpr (MODE == 4) {
                    float t = v + bias[col];
                    ((unsigned short*)outp)[(size_t)row * ldc + col] = f2bf(t > 0.f ? t : 0.f);
                } else {
                    float* o = (float*)outp;
                    const size_t ix = (size_t)row * ldc + col;
                    o[ix] = v + bias[col] + o[ix];
                }
            }
        }
    }
}

// ---------------- deformable sampling, v3 ----------------
// 8 tokens per block of 256. thread = (tk = tid>>5, h = (tid>>2)&7, c4 = tid&3).
// Each thread owns 8 channels (16B), packed float2 accumulate, padded LDS (stride 9,
// conflict-free staging + reads).
__global__ __launch_bounds__(256)
void deform_sample(const unsigned short* __restrict__ val,   // (BS,256) bf16
                   const float* __restrict__ loc,            // (BS,256) fp32  (h,l,p,c)
                   const float* __restrict__ attn,           // (BS,128) fp32  (h,l,p)
                   unsigned short* __restrict__ accb)        // (BS,256) bf16
{
    __shared__ float s_loc[8][32][9];    // [tk][pl*2+c][h] pad->9: staging conflict-free
    __shared__ float s_attn[8][16][9];   // [tk][pl][h]

    const int tid = threadIdx.x;
    const int t0  = blockIdx.x * 8;

    for (int i = tid; i < 8 * 256; i += 256) {
        const int tk = i >> 8, rem = i & 255;
        const int hh = rem >> 5, off = rem & 31;   // off = pl*2+c
        s_loc[tk][off][hh] = loc[(size_t)t0 * 256 + i];
    }
    for (int i = tid; i < 8 * 128; i += 256) {
        const int tk = i >> 7, rem = i & 127;
        const int hh = rem >> 4, pl = rem & 15;
        s_attn[tk][pl][hh] = attn[(size_t)t0 * 128 + i];
    }
    __syncthreads();

    const int c4 = tid & 3;
    const int h  = (tid >> 2) & 7;
    const int tk = tid >> 5;
    const int t  = t0 + tk;
    const int b  = t0 / Sn;                         // Sn % 8 == 0 -> whole block same batch

    const int sz[4] = {128, 64, 32, 16};
    const int st[4] = {0, 16384, 20480, 21504};

    const unsigned short* valh = val + ((size_t)b * Sn) * 256 + h * 32 + c4 * 8;

    const float* slh = &s_loc[tk][0][h];    // stride 9 floats per c2
    const float* sah = &s_attn[tk][0][h];   // stride 9 floats per pl

    f32x2 acc0 = {0.f, 0.f}, acc1 = {0.f, 0.f}, acc2a = {0.f, 0.f}, acc3 = {0.f, 0.f};

#pragma unroll
    for (int l = 0; l < 4; ++l) {
        const int W = sz[l];
        const float Wf = (float)W;
        const unsigned short* lptr = valh + (size_t)st[l] * 256;
#pragma unroll
        for (int p = 0; p < 4; ++p) {
            const int pl = l * 4 + p;
            const float aw = sah[pl * 9];
            const float fx = slh[(pl * 2) * 9]     * Wf - 0.5f;
            const float fy = slh[(pl * 2 + 1) * 9] * Wf - 0.5f;
            const float xf = floorf(fx), yf = floorf(fy);
            const float wx = fx - xf,  wy = fy - yf;
            const int x0 = (int)xf, y0 = (int)yf;
            const int x1 = x0 + 1,  y1 = y0 + 1;
            const float vx0 = (x0 >= 0 && x0 < W) ? 1.f : 0.f;
            const float vx1 = (x1 >= 0 && x1 < W) ? 1.f : 0.f;
            const float vy0 = (y0 >= 0 && y0 < W) ? 1.f : 0.f;
            const float vy1 = (y1 >= 0 && y1 < W) ? 1.f : 0.f;
            const int x0c = min(max(x0, 0), W - 1);
            const int x1c = min(max(x1, 0), W - 1);
            const int y0c = min(max(y0, 0), W - 1);
            const int y1c = min(max(y1, 0), W - 1);

            const float w00 = aw * (1.f - wx) * (1.f - wy) * vx0 * vy0;
            const float w01 = aw * wx         * (1.f - wy) * vx1 * vy0;
            const float w10 = aw * (1.f - wx) * wy         * vx0 * vy1;
            const float w11 = aw * wx         * wy         * vx1 * vy1;

            const uint4 u00 = *(const uint4*)(lptr + (size_t)((y0c * W + x0c) << 8));
            const uint4 u01 = *(const uint4*)(lptr + (size_t)((y0c * W + x1c) << 8));
            const uint4 u10 = *(const uint4*)(lptr + (size_t)((y1c * W + x0c) << 8));
            const uint4 u11 = *(const uint4*)(lptr + (size_t)((y1c * W + x1c) << 8));

            f32x2 wv;
            wv.x = w00; wv.y = w00;
            acc0 += wv * cvt2(u00.x); acc1 += wv * cvt2(u00.y);
            acc2a += wv * cvt2(u00.z); acc3 += wv * cvt2(u00.w);
            wv.x = w01; wv.y = w01;
            acc0 += wv * cvt2(u01.x); acc1 += wv * cvt2(u01.y);
            acc2a += wv * cvt2(u01.z); acc3 += wv * cvt2(u01.w);
            wv.x = w10; wv.y = w10;
            acc0 += wv * cvt2(u10.x); acc1 += wv * cvt2(u10.y);
            acc2a += wv * cvt2(u10.z); acc3 += wv * cvt2(u10.w);
            wv.x = w11; wv.y = w11;
            acc0 += wv * cvt2(u11.x); acc1 += wv * cvt2(u11.y);
            acc2a += wv * cvt2(u11.z); acc3 += wv * cvt2(u11.w);
        }
    }

    uint4 o;
    o.x = (unsigned int)f2bf(acc0.x) | ((unsigned int)f2bf(acc0.y) << 16);
    o.y = (unsigned int)f2bf(acc1.x) | ((unsigned int)f2bf(acc1.y) << 16);
    o.z = (unsigned int)f2bf(acc2a.x) | ((unsigned int)f2bf(acc2a.y) << 16);
    o.w = (unsigned int)f2bf(acc3.x) | ((unsigned int)f2bf(acc3.y) << 16);
    *(uint4*)(accb + (size_t)t * 256 + h * 32 + c4 * 8) = o;
}

// ---------------- layernorm over 256, in place on io; optional bf16 emit ----------------
template<bool EMIT>
__global__ __launch_bounds__(256)
void layernorm256(float* __restrict__ io, const float* __restrict__ g,
                  const float* __restrict__ bta, unsigned short* __restrict__ xb)
{
    const int row = blockIdx.x;
    const int c   = threadIdx.x;
    float v = io[(size_t)row * 256 + c];
    float s = v, s2 = v * v;
#pragma unroll
    for (int m = 1; m < 64; m <<= 1) {
        s  += __shfl_xor(s, m);
        s2 += __shfl_xor(s2, m);
    }
    __shared__ float sh[8];
    const int wv = c >> 6, lane = c & 63;
    if (lane == 0) { sh[wv] = s; sh[4 + wv] = s2; }
    __syncthreads();
    const float ts  = sh[0] + sh[1] + sh[2] + sh[3];
    const float ts2 = sh[4] + sh[5] + sh[6] + sh[7];
    const float mu  = ts * (1.f / 256.f);
    const float var = ts2 * (1.f / 256.f) - mu * mu;
    const float inv = rsqrtf(var + 1e-5f);
    const float y = (v - mu) * inv * g[c] + bta[c];
    io[(size_t)row * 256 + c] = y;
    if constexpr (EMIT) xb[(size_t)row * 256 + c] = f2bf(y);
}

// ---------------- launch ----------------
extern "C" void kernel_launch(void* const* d_in, const int* in_sizes, int n_in,
                              void* d_out, int out_size, void* d_ws, size_t ws_size,
                              hipStream_t stream) {
    const float* src    = (const float*)d_in[0];
    const float* pos    = (const float*)d_in[1];
    const float* refpts = (const float*)d_in[2];
    const float* W_off  = (const float*)d_in[5];
    const float* b_off  = (const float*)d_in[6];
    const float* W_attn = (const float*)d_in[7];
    const float* b_attn = (const float*)d_in[8];
    const float* W_val  = (const float*)d_in[9];
    const float* b_val  = (const float*)d_in[10];
    const float* W_out  = (const float*)d_in[11];
    const float* b_out  = (const float*)d_in[12];
    const float* W_ffn1 = (const float*)d_in[13];
    const float* b_ffn1 = (const float*)d_in[14];
    const float* W_ffn2 = (const float*)d_in[15];
    const float* b_ffn2 = (const float*)d_in[16];
    const float* ln1_g  = (const float*)d_in[17];
    const float* ln1_b  = (const float*)d_in[18];
    const float* ln2_g  = (const float*)d_in[19];
    const float* ln2_b  = (const float*)d_in[20];

    char* ws = (char*)d_ws;

    // weight arena (bf16, transposed N x K)
    unsigned short* wT      = (unsigned short*)ws;
    unsigned short* WvalT   = wT + 0;        // 256x256
    unsigned short* WoffT   = wT + 65536;    // 256x256
    unsigned short* WattnT  = wT + 131072;   // 128x256
    unsigned short* WoutT   = wT + 163840;   // 256x256
    unsigned short* Wffn1T  = wT + 229376;   // 1024x256
    unsigned short* Wffn2T  = wT + 491520;   // 256x1024

    constexpr size_t SZ_TOK_BF = (size_t)BS * 256 * 2;   // 22,282,240
    constexpr size_t SZ_TOK_F  = (size_t)BS * 256 * 4;   // 44,564,480
    const size_t o = 2u * 1024 * 1024;
    unsigned short* srcb  = (unsigned short*)(ws + o);                         // later: x_bf16
    unsigned short* qb    = (unsigned short*)(ws + o + SZ_TOK_BF);             // later: acc_bf16
    unsigned short* valb  = (unsigned short*)(ws + o + 2 * SZ_TOK_BF);         // later: h_bf16 overlay
    float*          locf  = (float*)(ws + o + 3 * SZ_TOK_BF);
    float*          attnf = (float*)(ws + o + 3 * SZ_TOK_BF + SZ_TOK_F);
    unsigned short* hb    = valb;   // 89,128,960 B overlays value+loc+attn exactly
    unsigned short* xb    = srcb;
    unsigned short* accb  = qb;

    float* out = (float*)d_out;

    // 1) weights: single fused transpose/convert kernel (753,664 elements)
    transpose_all<<<(753664 + 255) / 256, 256, 0, stream>>>(
        W_val, W_off, W_attn, W_out, W_ffn1, W_ffn2, wT);

    // 2) activations prep
    prep_q<<<4096, 256, 0, stream>>>(src, pos, srcb, qb, BS * 256);

    dim3 g1(1, BS / 128), g2(2, BS / 128), g8(8, BS / 128);
    // 3) value projection -> bf16
    gemm_mfma<0><<<g2, 256, 0, stream>>>(srcb, WvalT, 256, 256, b_val, nullptr, valb);
    // 4) offsets -> sampling locations (fused)
    gemm_mfma<1><<<g2, 256, 0, stream>>>(qb, WoffT, 256, 256, b_off, refpts, locf);
    // 5) attention logits + fused softmax
    gemm_mfma<2><<<g1, 256, 0, stream>>>(qb, WattnT, 256, 128, b_attn, nullptr, attnf);
    // 6) deformable bilinear sampling + weighted sum
    deform_sample<<<BS / 8, 256, 0, stream>>>(valb, locf, attnf, accb);
    // 7) output projection + residual (src) -> d_out (fp32)
    gemm_mfma<3><<<g2, 256, 0, stream>>>(accb, WoutT, 256, 256, b_out, src, out);
    // 8) LN1 in place, emit x bf16
    layernorm256<true><<<BS, 256, 0, stream>>>(out, ln1_g, ln1_b, xb);
    // 9) FFN1 + relu -> bf16
    gemm_mfma<4><<<g8, 256, 0, stream>>>(xb, Wffn1T, 256, 1024, b_ffn1, nullptr, hb);
    // 10) FFN2 + residual(x, read from d_out) -> d_out
    gemm_mfma<5><<<g2, 256, 0, stream>>>(hb, Wffn2T, 1024, 256, b_ffn2, nullptr, out);
    // 11) LN2 in place
    layernorm256<false><<<BS, 256, 0, stream>>>(out, ln2_g, ln2_b, nullptr);
}

// Round 4
// 508.732 us; speedup vs baseline: 2.6859x; 1.0394x over previous
//
#include <hip/hip_runtime.h>
#include <stdint.h>
#include <stddef.h>

// ---------------- problem constants ----------------
constexpr int Dm  = 256;
constexpr int NH  = 8;
constexpr int NL  = 4;
constexpr int NP  = 4;
constexpr int DFF = 1024;
constexpr int Bb  = 2;
constexpr int Sn  = 21760;            // 128*128 + 64*64 + 32*32 + 16*16
constexpr int BS  = Bb * Sn;          // 43520  (= 340 * 128 exactly)
constexpr int DH  = Dm / NH;          // 32

// ---------------- small helpers ----------------
__device__ __forceinline__ unsigned short f2bf(float f) {
    union { float f; unsigned int u; } v; v.f = f;
    unsigned int u = v.u;
    unsigned int r = u + 0x7FFFu + ((u >> 16) & 1u);   // round-nearest-even
    return (unsigned short)(r >> 16);
}

typedef float  f32x4  __attribute__((ext_vector_type(4)));
typedef float  f32x2  __attribute__((ext_vector_type(2)));
typedef __bf16 bf16x8 __attribute__((ext_vector_type(8)));

// unpack 2 bf16 (packed in u32) -> float2
__device__ __forceinline__ f32x2 cvt2(unsigned int u) {
    union { unsigned int u; float f; } lo, hi;
    lo.u = u << 16; hi.u = u & 0xFFFF0000u;
    f32x2 r; r.x = lo.f; r.y = hi.f; return r;
}

// address-space helpers for global_load_lds
typedef const __attribute__((address_space(1))) unsigned int GU;
typedef __attribute__((address_space(3))) unsigned int LU;
__device__ __forceinline__ void g2lds16(const void* g, void* l) {
    __builtin_amdgcn_global_load_lds((GU*)g, (LU*)l, 16, 0, 0);
}

// ---------------- all weights: convert + transpose in ONE kernel ----------------
// wT element layout (all N-major, [n][k]):
//   WprojT @0       : 640 x 256  (cols 0-255 W_val, 256-511 W_off, 512-639 W_attn)
//   WoutT  @163840  : 256 x 256
//   Wffn1T @229376  : 1024 x 256
//   Wffn2T @491520  : 256 x 1024
__global__ void transpose_all(const float* __restrict__ W_val, const float* __restrict__ W_off,
                              const float* __restrict__ W_attn, const float* __restrict__ W_out,
                              const float* __restrict__ W_ffn1, const float* __restrict__ W_ffn2,
                              unsigned short* __restrict__ wT) {
    int i = blockIdx.x * 256 + threadIdx.x;
    float v;
    if (i < 163840) {                       // proj block
        int n = i >> 8, k = i & 255;
        if      (n < 256) v = W_val[(size_t)k * 256 + n];
        else if (n < 512) v = W_off[(size_t)k * 256 + (n - 256)];
        else              v = W_attn[(size_t)k * 128 + (n - 512)];
    } else if (i < 229376) {
        int j = i - 163840, n = j >> 8, k = j & 255;
        v = W_out[(size_t)k * 256 + n];
    } else if (i < 491520) {
        int j = i - 229376, n = j >> 8, k = j & 255;
        v = W_ffn1[(size_t)k * 1024 + n];
    } else if (i < 753664) {
        int j = i - 491520, n = j >> 10, k = j & 1023;
        v = W_ffn2[(size_t)k * 256 + n];
    } else return;
    wT[i] = f2bf(v);
}

// ---------------- q = src+pos (bf16), src (bf16) ----------------
__global__ void prep_q(const float* __restrict__ src, const float* __restrict__ pos,
                       unsigned short* __restrict__ srcb, unsigned short* __restrict__ qb,
                       int ntot) {
    for (int i = blockIdx.x * blockDim.x + threadIdx.x; i < ntot; i += gridDim.x * blockDim.x) {
        float s = src[i];
        srcb[i] = f2bf(s);
        qb[i]   = f2bf(s + pos[i]);
    }
}

// ---------------- fused projection GEMM: value + offsets + attn(softmax) ----------------
// 128x128 tiles, K=256, grid (5, 340). bn 0-1: value (A=srcb) -> head-major bf16;
// bn 2-3: loc (A=qb); bn 4: attn+softmax (A=qb).
__global__ __launch_bounds__(256)
void gemm_proj(const unsigned short* __restrict__ srcb,
               const unsigned short* __restrict__ qb,
               const unsigned short* __restrict__ WprojT,
               const float* __restrict__ b_val, const float* __restrict__ b_off,
               const float* __restrict__ b_attn, const float* __restrict__ refpts,
               unsigned short* __restrict__ valb, float* __restrict__ locf,
               float* __restrict__ attnf)
{
    __shared__ __align__(16) unsigned short As[128 * 32];
    __shared__ __align__(16) unsigned short Bs[128 * 32];

    const int tid  = threadIdx.x;
    const int lane = tid & 63;
    const int w    = tid >> 6;
    const int quad = lane >> 4;
    const int r16  = lane & 15;
    const int wr   = w >> 1, wc = w & 1;
    const int bm   = blockIdx.y, bn = blockIdx.x;

    const unsigned short* A  = (bn < 2) ? srcb : qb;
    const unsigned short* BT = WprojT + (size_t)bn * 128 * 256;

    const int sr = tid >> 2;
    const int sc = (tid & 3) << 3;

    const unsigned short* gA0 = A  + (size_t)(bm * 128 + sr)      * 256 + sc;
    const unsigned short* gA1 = A  + (size_t)(bm * 128 + sr + 64) * 256 + sc;
    const unsigned short* gB0 = BT + (size_t)(sr)      * 256 + sc;
    const unsigned short* gB1 = BT + (size_t)(sr + 64) * 256 + sc;

    char* AsB = (char*)As;
    char* BsB = (char*)Bs;
    const int woff = w * 1024;

    f32x4 acc[4][4] = {};

    for (int k0 = 0; k0 < 256; k0 += 32) {
        __syncthreads();
        g2lds16(gA0 + k0, AsB + woff);
        g2lds16(gA1 + k0, AsB + 4096 + woff);
        g2lds16(gB0 + k0, BsB + woff);
        g2lds16(gB1 + k0, BsB + 4096 + woff);
        __syncthreads();

        bf16x8 af[4], bfr[4];
#pragma unroll
        for (int mt = 0; mt < 4; ++mt)
            af[mt] = *(const bf16x8*)&As[(wr * 64 + mt * 16 + r16) * 32 + quad * 8];
#pragma unroll
        for (int nt = 0; nt < 4; ++nt)
            bfr[nt] = *(const bf16x8*)&Bs[(wc * 64 + nt * 16 + r16) * 32 + quad * 8];
#pragma unroll
        for (int mt = 0; mt < 4; ++mt)
#pragma unroll
            for (int nt = 0; nt < 4; ++nt)
                acc[mt][nt] = __builtin_amdgcn_mfma_f32_16x16x32_bf16(
                    af[mt], bfr[nt], acc[mt][nt], 0, 0, 0);
    }

    const int mbase = bm * 128 + wr * 64 + quad * 4;
    const int nbase = bn * 128 + wc * 64 + r16;   // global col in 0..639
#pragma unroll
    for (int mt = 0; mt < 4; ++mt) {
#pragma unroll
        for (int nt = 0; nt < 4; ++nt) {
            const int col = nbase + nt * 16;
#pragma unroll
            for (int r = 0; r < 4; ++r) {
                const int row = mbase + mt * 16 + r;
                const float v = acc[mt][nt][r];
                if (bn < 2) {
                    // value, head-major: [b][h][pos][32ch]
                    const int b = (row >= Sn) ? 1 : 0;
                    const int srow = row - b * Sn;
                    const int h = col >> 5, ch = col & 31;
                    valb[(((size_t)b * 8 + h) * Sn + srow) * 32 + ch] =
                        f2bf(v + b_val[col]);
                } else if (bn < 4) {
                    const int c2 = col - 256;
                    const int c = c2 & 1;
                    const int l = (c2 >> 3) & 3;
                    const float invn = 1.f / (float)(128 >> l);
                    const float rp = refpts[(size_t)row * 8 + l * 2 + c];
                    locf[(size_t)row * 256 + c2] = rp + (v + b_off[c2]) * invn;
                } else {
                    const int c2 = col - 512;   // 0..127
                    float x = v + b_attn[c2];
                    float mx = x;
                    mx = fmaxf(mx, __shfl_xor(mx, 1));
                    mx = fmaxf(mx, __shfl_xor(mx, 2));
                    mx = fmaxf(mx, __shfl_xor(mx, 4));
                    mx = fmaxf(mx, __shfl_xor(mx, 8));
                    float e = __expf(x - mx);
                    float s = e;
                    s += __shfl_xor(s, 1);
                    s += __shfl_xor(s, 2);
                    s += __shfl_xor(s, 4);
                    s += __shfl_xor(s, 8);
                    attnf[(size_t)row * 128 + c2] = e / s;
                }
            }
        }
    }
}

// ---------------- ffn1 GEMM: 128x128 tiles, relu -> bf16 ----------------
__global__ __launch_bounds__(256)
void gemm_ffn1(const unsigned short* __restrict__ A,
               const unsigned short* __restrict__ BT,
               const float* __restrict__ bias,
               unsigned short* __restrict__ outp)
{
    __shared__ __align__(16) unsigned short As[128 * 32];
    __shared__ __align__(16) unsigned short Bs[128 * 32];

    const int tid  = threadIdx.x;
    const int lane = tid & 63;
    const int w    = tid >> 6;
    const int quad = lane >> 4;
    const int r16  = lane & 15;
    const int wr   = w >> 1, wc = w & 1;
    const int bm   = blockIdx.y, bn = blockIdx.x;

    const int sr = tid >> 2;
    const int sc = (tid & 3) << 3;

    const unsigned short* gA0 = A  + (size_t)(bm * 128 + sr)      * 256 + sc;
    const unsigned short* gA1 = A  + (size_t)(bm * 128 + sr + 64) * 256 + sc;
    const unsigned short* gB0 = BT + (size_t)(bn * 128 + sr)      * 256 + sc;
    const unsigned short* gB1 = BT + (size_t)(bn * 128 + sr + 64) * 256 + sc;

    char* AsB = (char*)As;
    char* BsB = (char*)Bs;
    const int woff = w * 1024;

    f32x4 acc[4][4] = {};

    for (int k0 = 0; k0 < 256; k0 += 32) {
        __syncthreads();
        g2lds16(gA0 + k0, AsB + woff);
        g2lds16(gA1 + k0, AsB + 4096 + woff);
        g2lds16(gB0 + k0, BsB + woff);
        g2lds16(gB1 + k0, BsB + 4096 + woff);
        __syncthreads();

        bf16x8 af[4], bfr[4];
#pragma unroll
        for (int mt = 0; mt < 4; ++mt)
            af[mt] = *(const bf16x8*)&As[(wr * 64 + mt * 16 + r16) * 32 + quad * 8];
#pragma unroll
        for (int nt = 0; nt < 4; ++nt)
            bfr[nt] = *(const bf16x8*)&Bs[(wc * 64 + nt * 16 + r16) * 32 + quad * 8];
#pragma unroll
        for (int mt = 0; mt < 4; ++mt)
#pragma unroll
            for (int nt = 0; nt < 4; ++nt)
                acc[mt][nt] = __builtin_amdgcn_mfma_f32_16x16x32_bf16(
                    af[mt], bfr[nt], acc[mt][nt], 0, 0, 0);
    }

    const int mbase = bm * 128 + wr * 64 + quad * 4;
    const int nbase = bn * 128 + wc * 64 + r16;
#pragma unroll
    for (int mt = 0; mt < 4; ++mt) {
#pragma unroll
        for (int nt = 0; nt < 4; ++nt) {
            const int col = nbase + nt * 16;
#pragma unroll
            for (int r = 0; r < 4; ++r) {
                const int row = mbase + mt * 16 + r;
                float t = acc[mt][nt][r] + bias[col];
                outp[(size_t)row * 1024 + col] = f2bf(t > 0.f ? t : 0.f);
            }
        }
    }
}

// ---------------- GEMM + residual + LayerNorm fused (64x256 tile, full row in block) ----
// MODE 0: out-proj: t = acc + bias + resid(src);  y = LN1(t); out=y fp32, xb=bf16(y)
// MODE 1: ffn2:     t = acc + bias + resid(x=d_out); y = LN2(t); out=y fp32
template<int MODE, int K>
__global__ __launch_bounds__(256)
void gemm_ln(const unsigned short* __restrict__ A,
             const unsigned short* __restrict__ BT,
             const float* __restrict__ bias,
             const float* __restrict__ gamma, const float* __restrict__ beta,
             const float* resid,
             float* out, unsigned short* __restrict__ xb)
{
    __shared__ __align__(16) unsigned short As[64 * 32];    // 4 KB
    __shared__ __align__(16) unsigned short Bs[256 * 32];   // 16 KB
    __shared__ float red[2][64][2];

    const int tid  = threadIdx.x;
    const int lane = tid & 63;
    const int w    = tid >> 6;
    const int quad = lane >> 4;
    const int r16  = lane & 15;
    const int wr   = w >> 1, wc = w & 1;   // wave tile 32 rows x 128 cols
    const int bm   = blockIdx.x;

    const int sr = tid >> 2;          // 0..63
    const int sc = (tid & 3) << 3;

    const unsigned short* gA  = A  + (size_t)(bm * 64 + (sr & 63)) * K + sc;
    const unsigned short* gB0 = BT + (size_t)(sr)       * K + sc;
    const unsigned short* gB1 = BT + (size_t)(sr + 64)  * K + sc;
    const unsigned short* gB2 = BT + (size_t)(sr + 128) * K + sc;
    const unsigned short* gB3 = BT + (size_t)(sr + 192) * K + sc;

    char* AsB = (char*)As;
    char* BsB = (char*)Bs;
    const int woff = w * 1024;

    f32x4 acc[2][8] = {};

    for (int k0 = 0; k0 < K; k0 += 32) {
        __syncthreads();
        g2lds16(gA  + k0, AsB + woff);
        g2lds16(gB0 + k0, BsB + woff);
        g2lds16(gB1 + k0, BsB + 4096  + woff);
        g2lds16(gB2 + k0, BsB + 8192  + woff);
        g2lds16(gB3 + k0, BsB + 12288 + woff);
        __syncthreads();

        bf16x8 af[2], bfr[8];
#pragma unroll
        for (int mt = 0; mt < 2; ++mt)
            af[mt] = *(const bf16x8*)&As[(wr * 32 + mt * 16 + r16) * 32 + quad * 8];
#pragma unroll
        for (int nt = 0; nt < 8; ++nt)
            bfr[nt] = *(const bf16x8*)&Bs[(wc * 128 + nt * 16 + r16) * 32 + quad * 8];
#pragma unroll
        for (int mt = 0; mt < 2; ++mt)
#pragma unroll
            for (int nt = 0; nt < 8; ++nt)
                acc[mt][nt] = __builtin_amdgcn_mfma_f32_16x16x32_bf16(
                    af[mt], bfr[nt], acc[mt][nt], 0, 0, 0);
    }

    // t = acc + bias + resid  (in place)
    const int rl_base = wr * 32 + quad * 4;
    const int cbase   = wc * 128 + r16;
#pragma unroll
    for (int mt = 0; mt < 2; ++mt)
#pragma unroll
        for (int nt = 0; nt < 8; ++nt) {
            const int col = cbase + nt * 16;
#pragma unroll
            for (int r = 0; r < 4; ++r) {
                const int rowl = rl_base + mt * 16 + r;
                const size_t gix = (size_t)(bm * 64 + rowl) * 256 + col;
                acc[mt][nt][r] += bias[col] + resid[gix];
            }
        }

    // per-row sums over this wave's 128 cols, then cross-wave via LDS
#pragma unroll
    for (int mt = 0; mt < 2; ++mt)
#pragma unroll
        for (int r = 0; r < 4; ++r) {
            float s = 0.f, s2 = 0.f;
#pragma unroll
            for (int nt = 0; nt < 8; ++nt) {
                const float v = acc[mt][nt][r];
                s += v; s2 += v * v;
            }
            s  += __shfl_xor(s, 1);  s2 += __shfl_xor(s2, 1);
            s  += __shfl_xor(s, 2);  s2 += __shfl_xor(s2, 2);
            s  += __shfl_xor(s, 4);  s2 += __shfl_xor(s2, 4);
            s  += __shfl_xor(s, 8);  s2 += __shfl_xor(s2, 8);
            if (r16 == 0) {
                const int rowl = rl_base + mt * 16 + r;
                red[wc][rowl][0] = s;
                red[wc][rowl][1] = s2;
            }
        }
    __syncthreads();

#pragma unroll
    for (int mt = 0; mt < 2; ++mt)
#pragma unroll
        for (int r = 0; r < 4; ++r) {
            const int rowl = rl_base + mt * 16 + r;
            const float ts  = red[0][rowl][0] + red[1][rowl][0];
            const float ts2 = red[0][rowl][1] + red[1][rowl][1];
            const float mu  = ts * (1.f / 256.f);
            const float var = ts2 * (1.f / 256.f) - mu * mu;
            const float inv = rsqrtf(var + 1e-5f);
#pragma unroll
            for (int nt = 0; nt < 8; ++nt) {
                const int col = cbase + nt * 16;
                const size_t gix = (size_t)(bm * 64 + rowl) * 256 + col;
                const float y = (acc[mt][nt][r] - mu) * inv * gamma[col] + beta[col];
                out[gix] = y;
                if constexpr (MODE == 0) xb[gix] = f2bf(y);
            }
        }
}

// ---------------- deformable sampling, v4: head-major value ----------------
// value layout: [b][h][pos][32ch]; x-adjacent corners 64 B apart -> line sharing.
__global__ __launch_bounds__(256)
void deform_sample(const unsigned short* __restrict__ val,   // (B,8,Sn,32) bf16
                   const float* __restrict__ loc,            // (BS,256) fp32  (h,l,p,c)
                   const float* __restrict__ attn,           // (BS,128) fp32  (h,l,p)
                   unsigned short* __restrict__ accb)        // (BS,256) bf16
{
    __shared__ float s_loc[8][32][9];
    __shared__ float s_attn[8][16][9];

    const int tid = threadIdx.x;
    const int t0  = blockIdx.x * 8;

    for (int i = tid; i < 8 * 256; i += 256) {
        const int tk = i >> 8, rem = i & 255;
        const int hh = rem >> 5, off = rem & 31;
        s_loc[tk][off][hh] = loc[(size_t)t0 * 256 + i];
    }
    for (int i = tid; i < 8 * 128; i += 256) {
        const int tk = i >> 7, rem = i & 127;
        const int hh = rem >> 4, pl = rem & 15;
        s_attn[tk][pl][hh] = attn[(size_t)t0 * 128 + i];
    }
    __syncthreads();

    const int c4 = tid & 3;
    const int h  = (tid >> 2) & 7;
    const int tk = tid >> 5;
    const int t  = t0 + tk;
    const int b  = t0 / Sn;

    const int sz[4] = {128, 64, 32, 16};
    const int st[4] = {0, 16384, 20480, 21504};

    // head-major base for (b,h), channel group c4
    const unsigned short* valh = val + ((size_t)(b * 8 + h) * Sn) * 32 + c4 * 8;

    const float* slh = &s_loc[tk][0][h];
    const float* sah = &s_attn[tk][0][h];

    f32x2 acc0 = {0.f, 0.f}, acc1 = {0.f, 0.f}, acc2a = {0.f, 0.f}, acc3 = {0.f, 0.f};

#pragma unroll
    for (int l = 0; l < 4; ++l) {
        const int W = sz[l];
        const float Wf = (float)W;
        const unsigned short* lptr = valh + (size_t)st[l] * 32;
#pragma unroll
        for (int p = 0; p < 4; ++p) {
            const int pl = l * 4 + p;
            const float aw = sah[pl * 9];
            const float fx = slh[(pl * 2) * 9]     * Wf - 0.5f;
            const float fy = slh[(pl * 2 + 1) * 9] * Wf - 0.5f;
            const float xf = floorf(fx), yf = floorf(fy);
            const float wx = fx - xf,  wy = fy - yf;
            const int x0 = (int)xf, y0 = (int)yf;
            const int x1 = x0 + 1,  y1 = y0 + 1;
            const float vx0 = (x0 >= 0 && x0 < W) ? 1.f : 0.f;
            const float vx1 = (x1 >= 0 && x1 < W) ? 1.f : 0.f;
            const float vy0 = (y0 >= 0 && y0 < W) ? 1.f : 0.f;
            const float vy1 = (y1 >= 0 && y1 < W) ? 1.f : 0.f;
            const int x0c = min(max(x0, 0), W - 1);
            const int x1c = min(max(x1, 0), W - 1);
            const int y0c = min(max(y0, 0), W - 1);
            const int y1c = min(max(y1, 0), W - 1);

            const float w00 = aw * (1.f - wx) * (1.f - wy) * vx0 * vy0;
            const float w01 = aw * wx         * (1.f - wy) * vx1 * vy0;
            const float w10 = aw * (1.f - wx) * wy         * vx0 * vy1;
            const float w11 = aw * wx         * wy         * vx1 * vy1;

            const uint4 u00 = *(const uint4*)(lptr + (size_t)(y0c * W + x0c) * 32);
            const uint4 u01 = *(const uint4*)(lptr + (size_t)(y0c * W + x1c) * 32);
            const uint4 u10 = *(const uint4*)(lptr + (size_t)(y1c * W + x0c) * 32);
            const uint4 u11 = *(const uint4*)(lptr + (size_t)(y1c * W + x1c) * 32);

            f32x2 wv;
            wv.x = w00; wv.y = w00;
            acc0 += wv * cvt2(u00.x); acc1 += wv * cvt2(u00.y);
            acc2a += wv * cvt2(u00.z); acc3 += wv * cvt2(u00.w);
            wv.x = w01; wv.y = w01;
            acc0 += wv * cvt2(u01.x); acc1 += wv * cvt2(u01.y);
            acc2a += wv * cvt2(u01.z); acc3 += wv * cvt2(u01.w);
            wv.x = w10; wv.y = w10;
            acc0 += wv * cvt2(u10.x); acc1 += wv * cvt2(u10.y);
            acc2a += wv * cvt2(u10.z); acc3 += wv * cvt2(u10.w);
            wv.x = w11; wv.y = w11;
            acc0 += wv * cvt2(u11.x); acc1 += wv * cvt2(u11.y);
            acc2a += wv * cvt2(u11.z); acc3 += wv * cvt2(u11.w);
        }
    }

    uint4 o;
    o.x = (unsigned int)f2bf(acc0.x) | ((unsigned int)f2bf(acc0.y) << 16);
    o.y = (unsigned int)f2bf(acc1.x) | ((unsigned int)f2bf(acc1.y) << 16);
    o.z = (unsigned int)f2bf(acc2a.x) | ((unsigned int)f2bf(acc2a.y) << 16);
    o.w = (unsigned int)f2bf(acc3.x) | ((unsigned int)f2bf(acc3.y) << 16);
    *(uint4*)(accb + (size_t)t * 256 + h * 32 + c4 * 8) = o;
}

// ---------------- launch ----------------
extern "C" void kernel_launch(void* const* d_in, const int* in_sizes, int n_in,
                              void* d_out, int out_size, void* d_ws, size_t ws_size,
                              hipStream_t stream) {
    const float* src    = (const float*)d_in[0];
    const float* pos    = (const float*)d_in[1];
    const float* refpts = (const float*)d_in[2];
    const float* W_off  = (const float*)d_in[5];
    const float* b_off  = (const float*)d_in[6];
    const float* W_attn = (const float*)d_in[7];
    const float* b_attn = (const float*)d_in[8];
    const float* W_val  = (const float*)d_in[9];
    const float* b_val  = (const float*)d_in[10];
    const float* W_out  = (const float*)d_in[11];
    const float* b_out  = (const float*)d_in[12];
    const float* W_ffn1 = (const float*)d_in[13];
    const float* b_ffn1 = (const float*)d_in[14];
    const float* W_ffn2 = (const float*)d_in[15];
    const float* b_ffn2 = (const float*)d_in[16];
    const float* ln1_g  = (const float*)d_in[17];
    const float* ln1_b  = (const float*)d_in[18];
    const float* ln2_g  = (const float*)d_in[19];
    const float* ln2_b  = (const float*)d_in[20];

    char* ws = (char*)d_ws;

    unsigned short* wT      = (unsigned short*)ws;
    unsigned short* WprojT  = wT + 0;        // 640x256
    unsigned short* WoutT   = wT + 163840;   // 256x256
    unsigned short* Wffn1T  = wT + 229376;   // 1024x256
    unsigned short* Wffn2T  = wT + 491520;   // 256x1024

    constexpr size_t SZ_TOK_BF = (size_t)BS * 256 * 2;
    constexpr size_t SZ_TOK_F  = (size_t)BS * 256 * 4;
    const size_t o = 2u * 1024 * 1024;
    unsigned short* srcb  = (unsigned short*)(ws + o);                         // later: x_bf16
    unsigned short* qb    = (unsigned short*)(ws + o + SZ_TOK_BF);             // later: acc_bf16
    unsigned short* valb  = (unsigned short*)(ws + o + 2 * SZ_TOK_BF);         // later: h_bf16 overlay
    float*          locf  = (float*)(ws + o + 3 * SZ_TOK_BF);
    float*          attnf = (float*)(ws + o + 3 * SZ_TOK_BF + SZ_TOK_F);
    unsigned short* hb    = valb;   // ffn hidden overlays value+loc+attn
    unsigned short* xb    = srcb;
    unsigned short* accb  = qb;

    float* out = (float*)d_out;

    // 1) weights
    transpose_all<<<(753664 + 255) / 256, 256, 0, stream>>>(
        W_val, W_off, W_attn, W_out, W_ffn1, W_ffn2, wT);

    // 2) activations prep
    prep_q<<<4096, 256, 0, stream>>>(src, pos, srcb, qb, BS * 256);

    // 3) fused projections: value(head-major) + loc + attn(softmax)
    gemm_proj<<<dim3(5, BS / 128), 256, 0, stream>>>(
        srcb, qb, WprojT, b_val, b_off, b_attn, refpts, valb, locf, attnf);

    // 4) deformable bilinear sampling + weighted sum
    deform_sample<<<BS / 8, 256, 0, stream>>>(valb, locf, attnf, accb);

    // 5) out-proj + residual(src) + LN1 -> out fp32 + xb bf16
    gemm_ln<0, 256><<<BS / 64, 256, 0, stream>>>(
        accb, WoutT, b_out, ln1_g, ln1_b, src, out, xb);

    // 6) FFN1 + relu -> bf16
    gemm_ffn1<<<dim3(8, BS / 128), 256, 0, stream>>>(xb, Wffn1T, b_ffn1, hb);

    // 7) FFN2 + residual(x=out) + LN2 -> out fp32 (final)
    gemm_ln<1, 1024><<<BS / 64, 256, 0, stream>>>(
        hb, Wffn2T, b_ffn2, ln2_g, ln2_b, out, out, nullptr);
}